// Round 1
// baseline (628.833 us; speedup 1.0000x reference)
//
#include <hip/hip_runtime.h>
#include <math.h>

#define NROWS 131072
#define NSEG  64
#define HH    512
#define LDK   40   // padded LDS row (ushorts): 80 B, 16B-aligned, breaks pow2 bank stride

typedef unsigned short u16;
typedef unsigned int   u32;
typedef __attribute__((ext_vector_type(8))) short short8;
typedef __attribute__((ext_vector_type(8))) u16   us8;
typedef __attribute__((ext_vector_type(4))) float f32x4;

__device__ __forceinline__ u32 f2u(float f){ union {float f; u32 u;} c; c.f=f; return c.u; }
__device__ __forceinline__ float u2f(u32 u){ union {u32 u; float f;} c; c.u=u; return c.f; }
__device__ __forceinline__ u16 bf16_rne(float f){
  u32 u = f2u(f);
  u32 r = u + 0x7FFFu + ((u >> 16) & 1u);
  return (u16)(r >> 16);
}
__device__ __forceinline__ float fast_tanh(float x){
  float e = __expf(2.0f * x);
  return 1.0f - __fdividef(2.0f, e + 1.0f);
}

// ---------------- hproj[b][j] = sum_k hidden[b][k] * W[j][k]  (W1 part, fp32 exact)
__global__ __launch_bounds__(256)
void hproj_kernel(const float* __restrict__ hidden, const float* __restrict__ W,
                  float* __restrict__ hproj)
{
  const int b   = blockIdx.x;
  const int tid = threadIdx.x;
  __shared__ float sh[HH];
  sh[tid]       = hidden[b * HH + tid];
  sh[tid + 256] = hidden[b * HH + tid + 256];
  __syncthreads();
  #pragma unroll
  for (int jj = 0; jj < 2; jj++) {
    const int j = jj * 256 + tid;
    const float* wrow = W + (size_t)j * 1024;
    float acc = 0.f;
    for (int k = 0; k < HH; k += 4) {
      float4 w4 = *(const float4*)(wrow + k);
      acc += sh[k] * w4.x + sh[k+1] * w4.y + sh[k+2] * w4.z + sh[k+3] * w4.w;
    }
    hproj[b * HH + j] = acc;
  }
}

// ---------------- split W2 = W[:, 512:1024] into bf16 hi/lo, row-major [j][k]
__global__ __launch_bounds__(256)
void w2split_kernel(const float* __restrict__ W, u16* __restrict__ hi, u16* __restrict__ lo)
{
  const int idx = blockIdx.x * 256 + threadIdx.x;   // j*512 + k
  const int j = idx >> 9, k = idx & 511;
  const float x = W[(size_t)j * 1024 + 512 + k];
  const u32 u = f2u(x);
  hi[idx] = (u16)(u >> 16);                         // truncation split
  lo[idx] = bf16_rne(x - u2f(u & 0xFFFF0000u));
}

// ---------------- main: scores[n] += sum_{j in col-tile} tanh(enc@W2.T + hproj) * v[j]
__global__ __launch_bounds__(256, 3)
void gemm_score_kernel(const float* __restrict__ enc,
                       const u16* __restrict__ w2hi,
                       const u16* __restrict__ w2lo,
                       const float* __restrict__ hproj,
                       const float* __restrict__ vvec,
                       const int* __restrict__ seg,
                       float* __restrict__ scores)
{
  __shared__ u16 sAhi[128 * LDK];
  __shared__ u16 sAlo[128 * LDK];
  __shared__ u16 sBhi[128 * LDK];
  __shared__ u16 sBlo[128 * LDK];

  const int tid  = threadIdx.x;
  const int bx   = blockIdx.x;
  const int row0 = (bx >> 2) * 128;   // col-tile fastest: A re-reads land in L3
  const int col0 = (bx & 3) * 128;

  const int wave = tid >> 6;
  const int lane = tid & 63;
  const int wr   = (wave >> 1) * 64;
  const int wc   = (wave & 1) * 64;
  const int l15  = lane & 15;
  const int quad = lane >> 4;

  const int sr = tid >> 1;            // staging row 0..127
  const int sk = (tid & 1) * 16;      // staging k-half

  f32x4 acc[4][4];
  #pragma unroll
  for (int i = 0; i < 4; i++)
    #pragma unroll
    for (int j = 0; j < 4; j++)
      acc[i][j] = (f32x4){0.f, 0.f, 0.f, 0.f};

  const float* gA  = enc  + (size_t)(row0 + sr) * HH + sk;
  const u16*   gBh = w2hi + (size_t)(col0 + sr) * HH + sk;
  const u16*   gBl = w2lo + (size_t)(col0 + sr) * HH + sk;
  u16* wAhi = &sAhi[sr * LDK + sk];
  u16* wAlo = &sAlo[sr * LDK + sk];
  u16* wBhi = &sBhi[sr * LDK + sk];
  u16* wBlo = &sBlo[sr * LDK + sk];

  for (int ks = 0; ks < HH; ks += 32) {
    // ---- stage A: fp32 -> bf16 hi/lo in-kernel ----
    float xb[16];
    *(float4*)(&xb[0])  = *(const float4*)(gA + ks + 0);
    *(float4*)(&xb[4])  = *(const float4*)(gA + ks + 4);
    *(float4*)(&xb[8])  = *(const float4*)(gA + ks + 8);
    *(float4*)(&xb[12]) = *(const float4*)(gA + ks + 12);
    u16 hb[16], lb[16];
    #pragma unroll
    for (int i = 0; i < 16; i++) {
      const u32 u = f2u(xb[i]);
      hb[i] = (u16)(u >> 16);
      lb[i] = bf16_rne(xb[i] - u2f(u & 0xFFFF0000u));
    }
    *(us8*)(wAhi)     = *(const us8*)&hb[0];
    *(us8*)(wAhi + 8) = *(const us8*)&hb[8];
    *(us8*)(wAlo)     = *(const us8*)&lb[0];
    *(us8*)(wAlo + 8) = *(const us8*)&lb[8];
    // ---- stage B: pre-split bf16, straight copy ----
    *(us8*)(wBhi)     = *(const us8*)(gBh + ks);
    *(us8*)(wBhi + 8) = *(const us8*)(gBh + ks + 8);
    *(us8*)(wBlo)     = *(const us8*)(gBl + ks);
    *(us8*)(wBlo + 8) = *(const us8*)(gBl + ks + 8);
    __syncthreads();

    // ---- fragments + 3-product MFMA ----
    short8 bhf[4], blf[4];
    #pragma unroll
    for (int j = 0; j < 4; j++) {
      const int br = (wc + j * 16 + l15) * LDK + quad * 8;
      bhf[j] = *(const short8*)&sBhi[br];
      blf[j] = *(const short8*)&sBlo[br];
    }
    #pragma unroll
    for (int i = 0; i < 4; i++) {
      const int ar = (wr + i * 16 + l15) * LDK + quad * 8;
      const short8 ah = *(const short8*)&sAhi[ar];
      const short8 al = *(const short8*)&sAlo[ar];
      #pragma unroll
      for (int j = 0; j < 4; j++) {
        acc[i][j] = __builtin_amdgcn_mfma_f32_16x16x32_bf16(ah, bhf[j], acc[i][j], 0, 0, 0);
        acc[i][j] = __builtin_amdgcn_mfma_f32_16x16x32_bf16(al, bhf[j], acc[i][j], 0, 0, 0);
        acc[i][j] = __builtin_amdgcn_mfma_f32_16x16x32_bf16(ah, blf[j], acc[i][j], 0, 0, 0);
      }
    }
    __syncthreads();
  }

  // ---- epilogue: + hproj, tanh, dot v, reduce over cols, atomicAdd per row ----
  int   jn[4];
  float vv[4];
  #pragma unroll
  for (int j = 0; j < 4; j++) { jn[j] = col0 + wc + j * 16 + l15; vv[j] = vvec[jn[j]]; }

  #pragma unroll
  for (int i = 0; i < 4; i++) {
    #pragma unroll
    for (int r = 0; r < 4; r++) {
      const int gn = row0 + wr + i * 16 + quad * 4 + r;    // C/D: row=(lane>>4)*4+reg
      const float* hp = hproj + (size_t)seg[gn] * HH;
      float p = 0.f;
      #pragma unroll
      for (int j = 0; j < 4; j++) {
        const float c = acc[i][j][r] + hp[jn[j]];
        p += fast_tanh(c) * vv[j];
      }
      p += __shfl_xor(p, 1);
      p += __shfl_xor(p, 2);
      p += __shfl_xor(p, 4);
      p += __shfl_xor(p, 8);
      if (l15 == 0) atomicAdd(&scores[gn], p);
    }
  }
}

// ---------------- segment softmax: one block per segment (ids sorted)
__global__ __launch_bounds__(256)
void seg_softmax_kernel(const float* __restrict__ scores, const int* __restrict__ seg,
                        float* __restrict__ out)
{
  const int b    = blockIdx.x;
  const int tid  = threadIdx.x;
  const int wv   = tid >> 6;
  const int lane = tid & 63;
  __shared__ float red[4];

  // lower_bound(b), lower_bound(b+1)
  int lo = 0, hi = NROWS;
  while (lo < hi) { int mid = (lo + hi) >> 1; if (seg[mid] < b) lo = mid + 1; else hi = mid; }
  const int start = lo;
  lo = 0; hi = NROWS;
  while (lo < hi) { int mid = (lo + hi) >> 1; if (seg[mid] < b + 1) lo = mid + 1; else hi = mid; }
  const int end = lo;

  float lm = -3.4e38f;
  for (int i = start + tid; i < end; i += 256) lm = fmaxf(lm, scores[i]);
  #pragma unroll
  for (int o = 32; o; o >>= 1) lm = fmaxf(lm, __shfl_xor(lm, o));
  if (lane == 0) red[wv] = lm;
  __syncthreads();
  const float gm = fmaxf(fmaxf(red[0], red[1]), fmaxf(red[2], red[3]));
  __syncthreads();

  float ls = 0.f;
  for (int i = start + tid; i < end; i += 256) ls += expf(scores[i] - gm);
  #pragma unroll
  for (int o = 32; o; o >>= 1) ls += __shfl_xor(ls, o);
  if (lane == 0) red[wv] = ls;
  __syncthreads();
  const float denom = red[0] + red[1] + red[2] + red[3];
  const float inv = 1.0f / denom;

  for (int i = start + tid; i < end; i += 256) out[i] = expf(scores[i] - gm) * inv;
}

extern "C" void kernel_launch(void* const* d_in, const int* in_sizes, int n_in,
                              void* d_out, int out_size, void* d_ws, size_t ws_size,
                              hipStream_t stream)
{
  const float* hidden = (const float*)d_in[0];
  const float* enc    = (const float*)d_in[1];
  const int*   seg    = (const int*)d_in[2];
  const float* W      = (const float*)d_in[3];
  const float* vvec   = (const float*)d_in[4];
  float* out = (float*)d_out;

  // ws layout: scores(512KB) | hproj(128KB) | w2hi(512KB) | w2lo(512KB)  ~1.7MB
  float* scores = (float*)d_ws;
  float* hproj  = scores + NROWS;
  u16*   w2hi   = (u16*)(hproj + NSEG * HH);
  u16*   w2lo   = w2hi + (size_t)HH * HH;

  hipMemsetAsync(scores, 0, NROWS * sizeof(float), stream);
  hproj_kernel<<<NSEG, 256, 0, stream>>>(hidden, W, hproj);
  w2split_kernel<<<(HH * HH) / 256, 256, 0, stream>>>(W, w2hi, w2lo);
  gemm_score_kernel<<<(NROWS / 128) * 4, 256, 0, stream>>>(enc, w2hi, w2lo, hproj, vvec, seg, scores);
  seg_softmax_kernel<<<NSEG, 256, 0, stream>>>(scores, seg, out);
}